// Round 4
// baseline (96.214 us; speedup 1.0000x reference)
//
#include <hip/hip_runtime.h>
#include <stdint.h>
#include <stddef.h>

// Problem constants (reference: M=16, K=8192, N=8192, GROUP=128)
#define MM 16
#define KK 8192
#define NN 8192
#define GROUP_SZ 128
#define NGROUP 64            // K / GROUP
#define KPACK 1024           // K / 8 packed int32 per output row
#define NWAVE 8              // waves per wq_main block
#define NCHUNK 8             // K chunks of 1024 (8 groups each, 1 group/wave)
#define LQS 132              // LDS row stride in ints (128 + 4 pad: bank-balanced)

typedef _Float16 half8_t __attribute__((ext_vector_type(8)));
typedef float float4_t __attribute__((ext_vector_type(4)));
typedef uint32_t uint4_t __attribute__((ext_vector_type(4)));
typedef int int4v __attribute__((ext_vector_type(4)));

// ---------------------------------------------------------------------------
// PRE (one launch, 528 blocks):
//  blocks 0..511  : pack x (fp32) into fp16 MFMA-A-fragment order:
//                   xf[(((g*4 + j)*64 + lane)*8 + slot)] =
//                     fp16( x[m = lane&15][ g*128 + (lane>>4)*32 + j*8 + perm[slot] ] )
//                   perm = {0,4,1,5,2,6,3,7} (nibble-unpack slot order).
//  blocks 512..527: exact per-(m,group) sums of the fp16-rounded x values
//                   (fp32 zero-point correction needs the SAME rounded values
//                   so the 1024-offset cancels exactly).
// ---------------------------------------------------------------------------
__global__ __launch_bounds__(256) void pre_x(const float* __restrict__ x,
                                             _Float16* __restrict__ xf,
                                             float* __restrict__ sxg) {
    const int b = blockIdx.x;
    if (b < 512) {
        const int i    = b * 256 + threadIdx.x;   // 0 .. 16*8192-1 (xf index)
        const int slot = i & 7;
        const int L    = (i >> 3) & 63;
        const int j    = (i >> 9) & 3;
        const int g    = i >> 11;
        const int m    = L & 15;
        const int quad = L >> 4;
        const int p    = (slot >> 1) | ((slot & 1) << 2);  // perm[slot]
        const int k    = g * GROUP_SZ + quad * 32 + j * 8 + p;
        xf[i] = (_Float16)x[m * KK + k];
    } else {
        const int m = b - 512;
        const int t = threadIdx.x;                 // covers k [t*32, t*32+32)
        const float4_t* xr = (const float4_t*)(x + (size_t)m * KK + t * 32);
        float s = 0.f;
        #pragma unroll
        for (int u = 0; u < 8; ++u) {
            float4_t v = xr[u];
            s += (float)(_Float16)v[0] + (float)(_Float16)v[1]
               + (float)(_Float16)v[2] + (float)(_Float16)v[3];
        }
        // 4 consecutive lanes = one group (128 k): cluster reduce
        s += __shfl_down(s, 2, 64);
        s += __shfl_down(s, 1, 64);
        if ((t & 3) == 0) sxg[m * NGROUP + (t >> 2)] = s;
    }
}

// ---------------------------------------------------------------------------
// MAIN: 512 blocks (one per 16-col n-tile) x 512 threads (8 waves).
// K processed in 8 chunks of 1024; per chunk the block cooperatively stages
// the 16-row x 128-int qweight tile into LDS with fully coalesced dwordx4
// loads (wave = 2 rows x 512 contiguous B, vs 64 scattered segments direct).
// Double-buffered: one barrier per chunk, global->reg prefetch 2 chunks ahead.
// Wave w consumes group c*8+w from LDS (b128, bank-balanced via 132-int row
// stride), dequants via (d>>4j & 0x000F000F) | 0x64006400, MFMA-accumulates,
// epilogue folds scale + exact fp32 zero-point correction (sxg in LDS).
// Cross-wave LDS reduce -> direct coalesced store with bias.
// ---------------------------------------------------------------------------
__global__ __launch_bounds__(512) void wq_main(
        const int* __restrict__ qweight,
        const float* __restrict__ scales,
        const float* __restrict__ zeros,
        const float* __restrict__ bias,
        const _Float16* __restrict__ xf,
        const float* __restrict__ sxg,
        float* __restrict__ out) {
    __shared__ int   lq[2][16 * LQS];    // 2 x 8.25 KB staged qweight
    __shared__ float red[NWAVE * 256];   // 8 KB cross-wave partials
    __shared__ float lsxg[MM * NGROUP];  // 4 KB

    const int t = threadIdx.x;
    lsxg[t]       = sxg[t];
    lsxg[t + 512] = sxg[t + 512];        // covered by first loop barrier

    const int w     = t >> 6;
    const int lane  = t & 63;
    const int ntile = blockIdx.x;
    const int nlo   = lane & 15;
    const int quad  = lane >> 4;
    const int n     = ntile * 16 + nlo;

    // staging role: thread t loads row (t>>5), ints [(t&31)*4 .. +4)
    const int srow = t >> 5;
    const int scol = t & 31;
    const int* sgp = qweight + (size_t)(ntile * 16 + srow) * KPACK + scol * 4;
    int* const sl0 = &lq[0][srow * LQS + scol * 4];
    int* const sl1 = &lq[1][srow * LQS + scol * 4];

    // per-wave LDS read base: row nlo, ints [(w*4+quad)*4 .. +4)
    const int* const rdp0 = &lq[0][nlo * LQS + (w * 4 + quad) * 4];
    const int* const rdp1 = &lq[1][nlo * LQS + (w * 4 + quad) * 4];

    // prologue: chunk 0 -> buf0, chunk 1 -> regs
    *(int4v*)sl0 = *(const int4v*)sgp;
    int4v r_next = *(const int4v*)(sgp + 128);

    float4_t outacc = {0.f, 0.f, 0.f, 0.f};

    #pragma unroll
    for (int c = 0; c < NCHUNK; ++c) {
        __syncthreads();   // buf[c&1] written; prior-chunk reads of buf[(c+1)&1] done
        const int4v r_cur = r_next;
        if (c + 2 < NCHUNK) r_next = *(const int4v*)(sgp + (c + 2) * 128);
        if (c + 1 < NCHUNK) *(int4v*)((c & 1) ? sl0 : sl1) = r_cur;

        const int gg  = c * 8 + w;                    // this wave's group
        const float s = scales[(size_t)gg * NN + n];
        const float z = zeros[(size_t)gg * NN + n];

        // B: 4 packed int32 = k-chunk [gg*128 + quad*32, +32), from LDS
        const uint4_t bw = *(const uint4_t*)((c & 1) ? rdp1 : rdp0);
        // A: fragment-ordered, lane-consecutive 16 B -> fully coalesced (L2)
        half8_t af[4];
        #pragma unroll
        for (int j = 0; j < 4; ++j)
            af[j] = *(const half8_t*)(xf + ((size_t)gg * 256 + j * 64 + lane) * 8);

        float4_t gacc = {0.f, 0.f, 0.f, 0.f};
        #pragma unroll
        for (int j = 0; j < 4; ++j) {
            const uint32_t d = bw[j];
            uint4_t bb;
            bb.x = ( d         & 0x000F000Fu) | 0x64006400u;  // nibbles (0,4)
            bb.y = ((d >> 4)   & 0x000F000Fu) | 0x64006400u;  // (1,5)
            bb.z = ((d >> 8)   & 0x000F000Fu) | 0x64006400u;  // (2,6)
            bb.w = ((d >> 12)  & 0x000F000Fu) | 0x64006400u;  // (3,7)
            gacc = __builtin_amdgcn_mfma_f32_16x16x32_f16(
                       af[j], __builtin_bit_cast(half8_t, bb), gacc, 0, 0, 0);
        }
        const float zc = z - 1024.0f * s;
        #pragma unroll
        for (int r = 0; r < 4; ++r)
            outacc[r] += s * gacc[r] + zc * lsxg[(quad * 4 + r) * NGROUP + gg];
    }

    // C/D layout: col = lane&15, row = quad*4 + r  -> red[w][row*16 + col]
    #pragma unroll
    for (int r = 0; r < 4; ++r)
        red[w * 256 + (quad * 4 + r) * 16 + nlo] = outacc[r];
    __syncthreads();

    if (t < 256) {
        const int m  = t >> 4;
        const int nn = t & 15;
        float v = bias[ntile * 16 + nn];
        #pragma unroll
        for (int ww = 0; ww < NWAVE; ++ww) v += red[ww * 256 + t];
        out[(size_t)m * NN + ntile * 16 + nn] = v;
    }
}

// ---------------------------------------------------------------------------
extern "C" void kernel_launch(void* const* d_in, const int* in_sizes, int n_in,
                              void* d_out, int out_size, void* d_ws, size_t ws_size,
                              hipStream_t stream) {
    const float* x      = (const float*)d_in[0];   // [16, 8192]
    const int*   qw     = (const int*)d_in[1];     // [8192, 1024]
    const float* scales = (const float*)d_in[2];   // [64, 8192]
    const float* zeros  = (const float*)d_in[3];   // [64, 8192]
    const float* bias   = (const float*)d_in[4];   // [8192]
    float* out = (float*)d_out;                    // [16, 8192] fp32

    // workspace: xf (16*8192 fp16 = 256KB, fragment-ordered) then sxg (4KB)
    _Float16* xf  = (_Float16*)d_ws;
    float*    sxg = (float*)((char*)d_ws + (size_t)MM * KK * sizeof(_Float16));

    pre_x<<<512 + MM, 256, 0, stream>>>(x, xf, sxg);
    wq_main<<<NN / 16, 512, 0, stream>>>(qw, scales, zeros, bias, xf, sxg, out);
}